// Round 4
// baseline (304.176 us; speedup 1.0000x reference)
//
#include <hip/hip_runtime.h>
#include <hip/hip_bf16.h>
#include <stdint.h>

#define U_ROWS 4096
#define P_DIM  1024
#define TM     256     // A-tile rows per block
#define TN     128     // B-tile rows (C cols) per block
#define BK     128     // fp8 bytes per k-tile (one K-window per MX MFMA)

typedef float f32x4 __attribute__((ext_vector_type(4)));
typedef int   i32x4 __attribute__((ext_vector_type(4)));
typedef int   i32x8 __attribute__((ext_vector_type(8)));

// Row L2-normalize (eps-clamped), scale by 16, emit OCP fp8 e4m3.
// Layout: within each 128-byte k-block, the 8 16-byte granules are
// rotated by (row & 7): granule g stored at ((g + row) & 7). This makes
// the GEMM's per-quad ds_read_b128 hit distinct bank groups across rows.
__global__ __launch_bounds__(256) void norm_fp8_kernel(
    const float* __restrict__ in1, const float* __restrict__ in2,
    uint8_t* __restrict__ out, float* __restrict__ loss_out) {
    const int w = threadIdx.x >> 6, lane = threadIdx.x & 63;
    const int row = blockIdx.x * 4 + w;
    const float* src = (row < U_ROWS) ? (in1 + (size_t)row * P_DIM)
                                      : (in2 + (size_t)(row - U_ROWS) * P_DIM);
    // lane owns the 16 consecutive elements [lane*16, lane*16+16)
    float4 v[4];
    float ss = 0.0f;
    #pragma unroll
    for (int j = 0; j < 4; ++j) {
        v[j] = ((const float4*)src)[lane * 4 + j];
        ss += v[j].x * v[j].x + v[j].y * v[j].y + v[j].z * v[j].z + v[j].w * v[j].w;
    }
    #pragma unroll
    for (int off = 32; off > 0; off >>= 1) ss += __shfl_xor(ss, off, 64);
    const float inv = 16.0f / fmaxf(sqrtf(ss), 1e-8f);

    i32x4 d;
    #pragma unroll
    for (int j = 0; j < 4; ++j) {
        int dj = __builtin_amdgcn_cvt_pk_fp8_f32(v[j].x * inv, v[j].y * inv, 0, false);
        dj = __builtin_amdgcn_cvt_pk_fp8_f32(v[j].z * inv, v[j].w * inv, dj, true);
        d[j] = dj;
    }
    const int blk = lane >> 3;                  // 128-byte k-block 0..7
    const int gi  = lane & 7;                   // granule within block
    uint8_t* orow = out + (size_t)row * P_DIM;
    *(i32x4*)(orow + blk * 128 + (((gi + row) & 7) * 16)) = d;
    if (blockIdx.x == 0 && threadIdx.x == 0) *loss_out = 0.0f;
}

// C = N1*N2^T fused with sum((1-c)^2), fp8 e4m3 scaled by 16 (acc=256*cos).
// 256x128 tile, 512 thr / 8 waves, wave = 64x64 via 4x4 MX MFMAs
// (16x16x128 f8f6f4, scale=1.0 -> E8M0 0x7F). BK=128: 8 K-iters.
// Staging: 48 KB/iter = 48 x 1KB global_load_lds chunks, 6/wave.
__global__ __launch_bounds__(512, 4) void cosloss_gemm_mx(
    const uint8_t* __restrict__ n1, const uint8_t* __restrict__ n2,
    float* __restrict__ loss_out) {
    __shared__ uint8_t As[TM * BK];   // 32 KB
    __shared__ uint8_t Bs[TN * BK];   // 16 KB
    __shared__ float red[8];

    const int tid  = threadIdx.x;
    const int w    = tid >> 6;        // 0..7
    const int lane = tid & 63;

    // XCD-aware swizzle (perf-only): id%8 -> XCD, 4-wide cb stripe per XCD.
    const int id  = blockIdx.x;       // 0..511
    const int xcd = id & 7;
    const int j   = id >> 3;          // 0..63
    const int cb  = xcd * 4 + (j & 3);  // 0..31
    const int rb  = j >> 2;             // 0..15

    const uint8_t* gA = n1 + (size_t)rb * TM * P_DIM;
    const uint8_t* gB = n2 + (size_t)cb * TN * P_DIM;

    // Staging: chunk = 8 rows x 128 B. Chunks 0..31 -> A, 32..47 -> B.
    const int srow = lane >> 3;          // 0..7
    const int scol = (lane & 7) * 16;    // byte col
    const int c0   = w * 6;

    f32x4 acc[4][4];
    #pragma unroll
    for (int mi = 0; mi < 4; ++mi)
        #pragma unroll
        for (int ni = 0; ni < 4; ++ni)
            acc[mi][ni] = (f32x4){0.f, 0.f, 0.f, 0.f};

    const int wr = (w >> 1) * 64;     // wave row origin (0..192)
    const int wc = (w & 1) * 64;      // wave col origin (0,64)
    const int fr = lane & 15;
    const int q  = lane >> 4;         // k-quad: lane covers k = q*32..q*32+31

    for (int kt = 0; kt < P_DIM / BK; ++kt) {
        #pragma unroll
        for (int cc = 0; cc < 6; ++cc) {
            const int c = c0 + cc;            // wave-uniform
            const uint8_t* g;
            uint8_t* s;
            if (c < 32) {
                g = gA + (size_t)(c * 8 + srow) * P_DIM + kt * BK + scol;
                s = As + c * 1024;
            } else {
                g = gB + (size_t)((c - 32) * 8 + srow) * P_DIM + kt * BK + scol;
                s = Bs + (c - 32) * 1024;
            }
            __builtin_amdgcn_global_load_lds(
                (const __attribute__((address_space(1))) void*)g,
                (__attribute__((address_space(3))) void*)s,
                16, 0, 0);
        }
        __syncthreads();

        // Fragments: lane needs 32 contiguous k-bytes = granules q*2, q*2+1,
        // stored rotated by (row & 7).
        i32x8 af[4];
        #pragma unroll
        for (int i = 0; i < 4; ++i) {
            const int row = wr + i * 16 + fr;
            const uint8_t* rbase = As + row * BK;
            i32x4 lo = *(const i32x4*)(rbase + (((q * 2 + 0 + row) & 7) * 16));
            i32x4 hi = *(const i32x4*)(rbase + (((q * 2 + 1 + row) & 7) * 16));
            af[i] = (i32x8){lo.x, lo.y, lo.z, lo.w, hi.x, hi.y, hi.z, hi.w};
        }
        #pragma unroll
        for (int ni = 0; ni < 4; ++ni) {
            const int row = wc + ni * 16 + fr;
            const uint8_t* rbase = Bs + row * BK;
            i32x4 lo = *(const i32x4*)(rbase + (((q * 2 + 0 + row) & 7) * 16));
            i32x4 hi = *(const i32x4*)(rbase + (((q * 2 + 1 + row) & 7) * 16));
            i32x8 bf = (i32x8){lo.x, lo.y, lo.z, lo.w, hi.x, hi.y, hi.z, hi.w};
            #pragma unroll
            for (int mi = 0; mi < 4; ++mi)
                acc[mi][ni] = __builtin_amdgcn_mfma_scale_f32_16x16x128_f8f6f4(
                    af[mi], bf, acc[mi][ni],
                    0, 0,            // cbsz=fp8, blgp=fp8
                    0, 0x7F,         // opsel_a, scale_a = 2^0
                    0, 0x7F);        // opsel_b, scale_b = 2^0
        }
        __syncthreads();
    }

    // Epilogue: acc = 256*cos -> sum (1 - acc/256)^2. Layout-agnostic.
    float local = 0.0f;
    #pragma unroll
    for (int mi = 0; mi < 4; ++mi)
        #pragma unroll
        for (int ni = 0; ni < 4; ++ni)
            #pragma unroll
            for (int r = 0; r < 4; ++r) {
                const float dd = 1.0f - acc[mi][ni][r] * (1.0f / 256.0f);
                local += dd * dd;
            }
    #pragma unroll
    for (int off = 32; off > 0; off >>= 1) local += __shfl_down(local, off, 64);
    if (lane == 0) red[w] = local;
    __syncthreads();
    if (tid == 0) {
        float t = 0.0f;
        #pragma unroll
        for (int i = 0; i < 8; ++i) t += red[i];
        atomicAdd(loss_out, t);
    }
}

extern "C" void kernel_launch(void* const* d_in, const int* in_sizes, int n_in,
                              void* d_out, int out_size, void* d_ws, size_t ws_size,
                              hipStream_t stream) {
    const float* in1 = (const float*)d_in[0];
    const float* in2 = (const float*)d_in[1];
    float* out = (float*)d_out;
    uint8_t* nrm = (uint8_t*)d_ws;                 // 8192x1024 fp8 = 8 MB

    norm_fp8_kernel<<<(U_ROWS * 2) / 4, 256, 0, stream>>>(in1, in2, nrm, out);

    cosloss_gemm_mx<<<(U_ROWS / TM) * (U_ROWS / TN), 512, 0, stream>>>(
        nrm, nrm + (size_t)U_ROWS * P_DIM, out);
}

// Round 5
// 119.051 us; speedup vs baseline: 2.5550x; 2.5550x over previous
//
#include <hip/hip_runtime.h>
#include <hip/hip_bf16.h>
#include <stdint.h>

#define U_ROWS 4096
#define P_DIM  1024
#define TILE   128     // square tile
#define BK     128     // fp8 bytes per k-window (one MX MFMA K)

typedef float f32x4 __attribute__((ext_vector_type(4)));
typedef int   i32x4 __attribute__((ext_vector_type(4)));
typedef int   i32x8 __attribute__((ext_vector_type(8)));

// Row L2-normalize (eps-clamped), scale by 16, emit OCP fp8 e4m3.
// Layout: within each 128-byte k-block, 16-byte granule g is stored at
// position g ^ (row & 7). The GEMM un-XORs at ds_read time; this spreads
// the per-quad reads across all 8 bank groups (perfectly balanced wave).
__global__ __launch_bounds__(256) void norm_fp8_kernel(
    const float* __restrict__ in1, const float* __restrict__ in2,
    uint8_t* __restrict__ out, float* __restrict__ loss_out) {
    const int w = threadIdx.x >> 6, lane = threadIdx.x & 63;
    const int row = blockIdx.x * 4 + w;
    const float* src = (row < U_ROWS) ? (in1 + (size_t)row * P_DIM)
                                      : (in2 + (size_t)(row - U_ROWS) * P_DIM);
    // lane owns 16 consecutive elements [lane*16, lane*16+16)
    float4 v[4];
    float ss = 0.0f;
    #pragma unroll
    for (int j = 0; j < 4; ++j) {
        v[j] = ((const float4*)src)[lane * 4 + j];
        ss += v[j].x * v[j].x + v[j].y * v[j].y + v[j].z * v[j].z + v[j].w * v[j].w;
    }
    #pragma unroll
    for (int off = 32; off > 0; off >>= 1) ss += __shfl_xor(ss, off, 64);
    const float inv = 16.0f / fmaxf(sqrtf(ss), 1e-8f);

    i32x4 d;
    #pragma unroll
    for (int j = 0; j < 4; ++j) {
        int dj = __builtin_amdgcn_cvt_pk_fp8_f32(v[j].x * inv, v[j].y * inv, 0, false);
        dj = __builtin_amdgcn_cvt_pk_fp8_f32(v[j].z * inv, v[j].w * inv, dj, true);
        d[j] = dj;
    }
    const int blk = lane >> 3;                  // 128-byte k-block 0..7
    const int gi  = lane & 7;                   // granule within block
    uint8_t* orow = out + (size_t)row * P_DIM;
    *(i32x4*)(orow + blk * 128 + ((gi ^ (row & 7)) * 16)) = d;
    if (blockIdx.x == 0 && threadIdx.x == 0) *loss_out = 0.0f;
}

// C = N1*N2^T fused with sum((1-c)^2), fp8 e4m3 scaled by 16 (acc=256*cos).
// 128x128 tile, 256 thr / 4 waves, wave = 64x64 via 4x4 MX MFMAs
// (16x16x128 f8f6f4, scales pinned to 1.0 = E8M0 0x7F). 8 K-windows.
// Staging 32 KB/window = 32 x 1KB global_load_lds chunks, 8/wave.
// NOTE: no min-waves in __launch_bounds__ — round 4's (512,4) capped VGPRs
// at 64 and spilled ~70 regs to scratch (456 MB WRITE_SIZE, 7x slowdown).
__global__ __launch_bounds__(256) void cosloss_gemm_mx(
    const uint8_t* __restrict__ n1, const uint8_t* __restrict__ n2,
    float* __restrict__ loss_out) {
    __shared__ uint8_t As[TILE * BK];   // 16 KB
    __shared__ uint8_t Bs[TILE * BK];   // 16 KB
    __shared__ float red[4];

    const int tid  = threadIdx.x;
    const int w    = tid >> 6;        // 0..3
    const int lane = tid & 63;

    // XCD-aware swizzle (perf-only): id%8 -> XCD, 4-wide cb stripe per XCD.
    const int id  = blockIdx.x;       // 0..1023
    const int xcd = id & 7;
    const int j   = id >> 3;          // 0..127
    const int cb  = xcd * 4 + (j & 3);  // 0..31
    const int rb  = j >> 2;             // 0..31

    const uint8_t* gA = n1 + (size_t)rb * TILE * P_DIM;
    const uint8_t* gB = n2 + (size_t)cb * TILE * P_DIM;

    // Staging: chunk = 8 rows x 128 B. Chunks 0..15 -> A, 16..31 -> B.
    const int srow = lane >> 3;          // 0..7
    const int scol = (lane & 7) * 16;    // byte col within 128-B k-window
    const int c0   = w * 8;

    f32x4 acc[4][4];
    #pragma unroll
    for (int mi = 0; mi < 4; ++mi)
        #pragma unroll
        for (int ni = 0; ni < 4; ++ni)
            acc[mi][ni] = (f32x4){0.f, 0.f, 0.f, 0.f};

    const int wr = (w >> 1) * 64;     // wave row origin (0,64)
    const int wc = (w & 1) * 64;      // wave col origin (0,64)
    const int fr = lane & 15;
    const int q  = lane >> 4;         // lane covers k = q*32 .. q*32+31

    for (int kt = 0; kt < P_DIM / BK; ++kt) {
        #pragma unroll
        for (int cc = 0; cc < 8; ++cc) {
            const int c = c0 + cc;            // wave-uniform
            const uint8_t* g;
            uint8_t* s;
            if (c < 16) {
                g = gA + (size_t)(c * 8 + srow) * P_DIM + kt * BK + scol;
                s = As + c * 1024;
            } else {
                g = gB + (size_t)((c - 16) * 8 + srow) * P_DIM + kt * BK + scol;
                s = Bs + (c - 16) * 1024;
            }
            __builtin_amdgcn_global_load_lds(
                (const __attribute__((address_space(1))) void*)g,
                (__attribute__((address_space(3))) void*)s,
                16, 0, 0);
        }
        __syncthreads();

        // Cache B fragments (32 VGPRs); stream A per mi (8 VGPRs live).
        i32x8 bf[4];
        #pragma unroll
        for (int ni = 0; ni < 4; ++ni) {
            const int row = wc + ni * 16 + fr;
            const uint8_t* rbase = Bs + row * BK;
            i32x4 lo = *(const i32x4*)(rbase + (((2 * q + 0) ^ (row & 7)) * 16));
            i32x4 hi = *(const i32x4*)(rbase + (((2 * q + 1) ^ (row & 7)) * 16));
            bf[ni] = (i32x8){lo.x, lo.y, lo.z, lo.w, hi.x, hi.y, hi.z, hi.w};
        }
        #pragma unroll
        for (int mi = 0; mi < 4; ++mi) {
            const int row = wr + mi * 16 + fr;
            const uint8_t* rbase = As + row * BK;
            i32x4 lo = *(const i32x4*)(rbase + (((2 * q + 0) ^ (row & 7)) * 16));
            i32x4 hi = *(const i32x4*)(rbase + (((2 * q + 1) ^ (row & 7)) * 16));
            i32x8 af = (i32x8){lo.x, lo.y, lo.z, lo.w, hi.x, hi.y, hi.z, hi.w};
            #pragma unroll
            for (int ni = 0; ni < 4; ++ni)
                acc[mi][ni] = __builtin_amdgcn_mfma_scale_f32_16x16x128_f8f6f4(
                    af, bf[ni], acc[mi][ni],
                    0, 0,            // cbsz=fp8, blgp=fp8
                    0, 0x7F,         // opsel_a, scale_a = 2^0
                    0, 0x7F);        // opsel_b, scale_b = 2^0
        }
        __syncthreads();
    }

    // Epilogue: acc = 256*cos -> sum (1 - acc/256)^2. Layout-agnostic.
    float local = 0.0f;
    #pragma unroll
    for (int mi = 0; mi < 4; ++mi)
        #pragma unroll
        for (int ni = 0; ni < 4; ++ni)
            #pragma unroll
            for (int r = 0; r < 4; ++r) {
                const float dd = 1.0f - acc[mi][ni][r] * (1.0f / 256.0f);
                local += dd * dd;
            }
    #pragma unroll
    for (int off = 32; off > 0; off >>= 1) local += __shfl_down(local, off, 64);
    if (lane == 0) red[w] = local;
    __syncthreads();
    if (tid == 0)
        atomicAdd(loss_out, red[0] + red[1] + red[2] + red[3]);
}

extern "C" void kernel_launch(void* const* d_in, const int* in_sizes, int n_in,
                              void* d_out, int out_size, void* d_ws, size_t ws_size,
                              hipStream_t stream) {
    const float* in1 = (const float*)d_in[0];
    const float* in2 = (const float*)d_in[1];
    float* out = (float*)d_out;
    uint8_t* nrm = (uint8_t*)d_ws;                 // 8192x1024 fp8 = 8 MB

    norm_fp8_kernel<<<(U_ROWS * 2) / 4, 256, 0, stream>>>(in1, in2, nrm, out);

    cosloss_gemm_mx<<<(U_ROWS / TILE) * (U_ROWS / TILE), 256, 0, stream>>>(
        nrm, nrm + (size_t)U_ROWS * P_DIM, out);
}